// Round 7
// baseline (336.194 us; speedup 1.0000x reference)
//
#include <hip/hip_runtime.h>

#define T_TOKENS 16384
#define CAP 12288     // per-expert bucket capacity; expected ~4096
#define CNT_STRIDE 16 // one 64B cacheline per counter
#define GRID_MEGA 264 // <= 2 blocks/CU capacity (LDS 49.4KB, VGPR<=256) -> always co-resident

typedef unsigned short u16;
typedef unsigned int u32;
typedef __attribute__((ext_vector_type(8))) short short8;
typedef __attribute__((ext_vector_type(4))) float float4v;

__device__ __forceinline__ u16 f2b(float f) {
  unsigned u = __float_as_uint(f);
  u = (u + 0x7fffu + ((u >> 16) & 1u)) >> 16;   // RNE fp32 -> bf16
  return (u16)u;
}
__device__ __forceinline__ float b2f(u16 h) {
  return __uint_as_float(((unsigned)h) << 16);
}

// async global->LDS, 16B/lane; LDS dest = wave-uniform base + lane*16
__device__ __forceinline__ void gl_lds16(const u16* g, u16* l) {
  __builtin_amdgcn_global_load_lds((const __attribute__((address_space(1))) u32*)g,
                                   (__attribute__((address_space(3))) u32*)l, 16, 0, 0);
}

// manual grid barrier: per-phase counter (zeroed by the memset dispatch each call).
// release-fence + device-scope arrive; acquire spin (invalidates stale L1/L2 lines).
// Safe: grid <= resident capacity (see GRID_MEGA).
__device__ __forceinline__ void grid_barrier(int* bar, int nblk) {
  __syncthreads();
  if (threadIdx.x == 0) {
    __threadfence();
    __hip_atomic_fetch_add(bar, 1, __ATOMIC_ACQ_REL, __HIP_MEMORY_SCOPE_AGENT);
    while (__hip_atomic_load(bar, __ATOMIC_ACQUIRE, __HIP_MEMORY_SCOPE_AGENT) < nblk)
      __builtin_amdgcn_s_sleep(8);
  }
  __syncthreads();
}

// ---------------- fused prep: route (blocks 0..63) || W fp32->bf16 (blocks 64..255) ----------------
__global__ __launch_bounds__(256) void prep_kernel(
    const int* __restrict__ m1, const int* __restrict__ m2, const int* __restrict__ m3,
    const float* __restrict__ rw1, const float* __restrict__ rw2, const float* __restrict__ rw3,
    const float* __restrict__ W1, const float* __restrict__ W2, const float* __restrict__ W3,
    u16* __restrict__ Wb1, u16* __restrict__ Wb2, u16* __restrict__ Wb3,
    int* __restrict__ cnt, int* __restrict__ idxbuf, float* __restrict__ wgtbuf) {
  const int tid = threadIdx.x;
  const int bid = blockIdx.x;
  if (bid < 64) {
    __shared__ int lcnt[24];
    __shared__ int lbase[24];
    if (tid < 24) lcnt[tid] = 0;
    __syncthreads();
    const int t = bid * 256 + tid;
    const int* masks[3] = {m1, m2, m3};
    const float* rws[3] = {rw1, rw2, rw3};
    int expert[3][2], lpos[3][2];
#pragma unroll
    for (int s = 0; s < 3; ++s)
#pragma unroll
      for (int k = 0; k < 2; ++k) {
        int e = 0;
#pragma unroll
        for (int j = 0; j < 8; ++j)
          if (masks[s][(j * 2 + k) * T_TOKENS + t] != 0) e = j;
        expert[s][k] = e;
        lpos[s][k] = atomicAdd(&lcnt[s * 8 + e], 1);
      }
    __syncthreads();
    if (tid < 24) lbase[tid] = atomicAdd(&cnt[tid * CNT_STRIDE], lcnt[tid]);
    __syncthreads();
#pragma unroll
    for (int s = 0; s < 3; ++s)
#pragma unroll
      for (int k = 0; k < 2; ++k) {
        int e = expert[s][k];
        int p = lbase[s * 8 + e] + lpos[s][k];
        if (p < CAP) {
          idxbuf[(s * 8 + e) * CAP + p] = t * 2 + k;
          wgtbuf[(s * 8 + e) * CAP + p] = rws[s][t * 2 + k];
        }
      }
  } else {
    // W1:1048576, W2:524288, W3:1048576 elems; 1280 jobs x 2048 elems over 192 blocks
    for (int j = bid - 64; j < 1280; j += 192) {
      int base = j * 2048 + tid * 8;
      const float* src; u16* dst; int off = base;
      if (base < 1048576) { src = W1; dst = Wb1; }
      else if (base < 1572864) { src = W2; dst = Wb2; off = base - 1048576; }
      else { src = W3; dst = Wb3; off = base - 1572864; }
      float4 a0 = *(const float4*)(src + off);
      float4 a1 = *(const float4*)(src + off + 4);
      short8 v;
      v[0] = (short)f2b(a0.x); v[1] = (short)f2b(a0.y);
      v[2] = (short)f2b(a0.z); v[3] = (short)f2b(a0.w);
      v[4] = (short)f2b(a1.x); v[5] = (short)f2b(a1.y);
      v[6] = (short)f2b(a1.z); v[7] = (short)f2b(a1.w);
      *(short8*)(dst + off) = v;
    }
  }
}

// ---- one grouped gather-GEMM stage, job-looped (128 rows x 256 cols / job) ----
// Math identical to the round-6-verified moe_gemm. XOR-swizzled LDS (16B granules):
// logical granule lg of row r at physical lg^(r&7); required for global_load_lds.
// SRC==0: A gathered from fp32 x, converted in VGPRs. SRC==1: A = slot0+slot1 of prev tmp.
template <int KDIM, int NDIM_TOTAL, int SRC, int RELU>
__device__ void gemm_stage(const void* __restrict__ Asrc_, const u16* __restrict__ Wb,
                           const float* __restrict__ bias, const int* __restrict__ cnt,
                           const int* __restrict__ idxbuf, const float* __restrict__ wgtbuf,
                           u16* __restrict__ outTmp, u16* As, u16* Bs, int* rowTok, float* rowW) {
  constexpr int NB = NDIM_TOTAL / 256;
  const int tid = threadIdx.x;
  const int wv = tid >> 6, lane = tid & 63;
  const int lrow = lane & 15, lquad = lane >> 4;
  const int mh = wv >> 1, nh = wv & 1;
  const int lr = lane >> 3, lgl = (lane & 7) ^ lr;

  int n_arr[8], nb_arr[8], tot = 0;
#pragma unroll
  for (int j = 0; j < 8; ++j) {
    int nj = cnt[j * CNT_STRIDE];
    nj = nj > CAP ? CAP : nj;
    n_arr[j] = nj;
    nb_arr[j] = (nj + 127) >> 7;
    tot += nb_arr[j];
  }
  const int njobs = tot * NB;

  for (int job = blockIdx.x; job < njobs; job += gridDim.x) {
    int rb = job, nbase = 0;
    if (NB == 2 && job >= tot) { rb = job - tot; nbase = 256; }
    int ee = 0, row0 = 0, n_e = 0, a = 0;
#pragma unroll
    for (int j = 0; j < 8; ++j) {
      if (rb >= a && rb < a + nb_arr[j]) { ee = j; row0 = (rb - a) << 7; n_e = n_arr[j]; }
      a += nb_arr[j];
    }
    if (tid < 128) {
      int g = row0 + tid;
      bool ok = g < n_e;
      rowTok[tid] = ok ? idxbuf[ee * CAP + g] : 0;
      rowW[tid] = ok ? wgtbuf[ee * CAP + g] : 0.f;
    }
    __syncthreads();

    const u16* Wbe = Wb + ((size_t)ee * NDIM_TOTAL + nbase) * KDIM;
    const u16* gB = Wbe + (size_t)(wv * 8 + lr) * KDIM + lgl * 8;

    float4v acc[4][8];
#pragma unroll
    for (int mt = 0; mt < 4; ++mt)
#pragma unroll
      for (int nt = 0; nt < 8; ++nt) acc[mt][nt] = (float4v)0.f;

    for (int kb = 0; kb < KDIM; kb += 64) {
      // B tile (256x64): async DMA
#pragma unroll
      for (int i = 0; i < 8; ++i)
        gl_lds16(gB + (size_t)i * 32 * KDIM + kb, &Bs[(wv * 8 + i * 32) * 64]);
      // A tile (128x64): VGPR path
#pragma unroll
      for (int i = 0; i < 4; ++i) {
        int row = i * 32 + (tid >> 3), lg = tid & 7, ph = lg ^ (row & 7);
        short8 v;
        if (SRC == 0) {
          const float* xp = (const float*)Asrc_ + (size_t)(rowTok[row] >> 1) * KDIM + kb + lg * 8;
          float4 a0 = *(const float4*)xp;
          float4 a1 = *(const float4*)(xp + 4);
          v[0] = (short)f2b(a0.x); v[1] = (short)f2b(a0.y);
          v[2] = (short)f2b(a0.z); v[3] = (short)f2b(a0.w);
          v[4] = (short)f2b(a1.x); v[5] = (short)f2b(a1.y);
          v[6] = (short)f2b(a1.z); v[7] = (short)f2b(a1.w);
        } else {
          const u16* p0 = (const u16*)Asrc_ + (size_t)(rowTok[row] >> 1) * 2 * KDIM + kb + lg * 8;
          short8 v0 = *(const short8*)p0;
          short8 v1 = *(const short8*)(p0 + KDIM);
#pragma unroll
          for (int jj = 0; jj < 8; ++jj)
            v[jj] = (short)f2b(b2f((u16)v0[jj]) + b2f((u16)v1[jj]));
        }
        *(short8*)&As[(row * 8 + ph) * 8] = v;
      }
      __syncthreads();
#pragma unroll
      for (int ks = 0; ks < 64; ks += 32) {
        const int gb = ks >> 3;
        short8 af[4], bf[8];
#pragma unroll
        for (int mt = 0; mt < 4; ++mt) {
          int r = mh * 64 + mt * 16 + lrow;
          int p = (gb + lquad) ^ (lrow & 7);
          af[mt] = *(const short8*)&As[(r * 8 + p) * 8];
        }
#pragma unroll
        for (int nt = 0; nt < 8; ++nt) {
          int r = nh * 128 + nt * 16 + lrow;
          int p = (gb + lquad) ^ (lrow & 7);
          bf[nt] = *(const short8*)&Bs[(r * 8 + p) * 8];
        }
#pragma unroll
        for (int mt = 0; mt < 4; ++mt)
#pragma unroll
          for (int nt = 0; nt < 8; ++nt)
            acc[mt][nt] = __builtin_amdgcn_mfma_f32_16x16x32_bf16(af[mt], bf[nt], acc[mt][nt], 0, 0, 0);
      }
      __syncthreads();
    }

    // epilogue: w * (relu?)(dot + bias) -> scatter bf16
    float bv[8];
#pragma unroll
    for (int nt = 0; nt < 8; ++nt)
      bv[nt] = bias[ee * NDIM_TOTAL + nbase + nh * 128 + nt * 16 + lrow];
#pragma unroll
    for (int mt = 0; mt < 4; ++mt)
#pragma unroll
      for (int i = 0; i < 4; ++i) {
        int m = mh * 64 + mt * 16 + lquad * 4 + i;
        if (row0 + m < n_e) {
          float w = rowW[m];
          size_t drow = (size_t)rowTok[m] * NDIM_TOTAL + nbase + nh * 128;
#pragma unroll
          for (int nt = 0; nt < 8; ++nt) {
            float v = acc[mt][nt][i] + bv[nt];
            if (RELU) v = fmaxf(v, 0.f);
            outTmp[drow + nt * 16 + lrow] = f2b(v * w);
          }
        }
      }
    __syncthreads();  // protect rowTok/rowW before next job overwrites
  }
}

// ---------------- mega kernel: stage1 -> stage2 -> stage3 -> finalize ----------------
extern "C" __global__ void __launch_bounds__(256, 2) moe_mega(
    const float* __restrict__ x, const float* __restrict__ b1, const float* __restrict__ b2,
    const float* __restrict__ b3, float* __restrict__ out, int* __restrict__ cnt,
    int* __restrict__ bars, u16* __restrict__ Wb1, u16* __restrict__ Wb2,
    u16* __restrict__ Wb3, u16* __restrict__ tmp1, u16* __restrict__ tmp2,
    u16* __restrict__ tmp3, int* __restrict__ idxb, float* __restrict__ wgtb) {
  __shared__ __align__(16) u16 As[128 * 64];   // 16 KB
  __shared__ __align__(16) u16 Bs[256 * 64];   // 32 KB
  __shared__ int rowTok[128];
  __shared__ float rowW[128];

  gemm_stage<512, 256, 0, 0>(x, Wb1, b1, cnt, idxb, wgtb, tmp1, As, Bs, rowTok, rowW);
  grid_barrier(&bars[0], GRID_MEGA);
  gemm_stage<256, 256, 1, 0>(tmp1, Wb2, b2, cnt + 8 * CNT_STRIDE, idxb + 8 * CAP,
                             wgtb + 8 * CAP, tmp2, As, Bs, rowTok, rowW);
  grid_barrier(&bars[1], GRID_MEGA);
  gemm_stage<256, 512, 1, 1>(tmp2, Wb3, b3, cnt + 16 * CNT_STRIDE, idxb + 16 * CAP,
                             wgtb + 16 * CAP, tmp3, As, Bs, rowTok, rowW);
  grid_barrier(&bars[2], GRID_MEGA);

  // finalize: out = relu(tmp3[t][0] + tmp3[t][1]), grid-stride
  const int tid = threadIdx.x;
  for (int i = blockIdx.x * 256 + tid; i < T_TOKENS * 512 / 8; i += GRID_MEGA * 256) {
    int f = i * 8, t = f >> 9, o = f & 511;
    const u16* p = tmp3 + (size_t)t * 1024 + o;
    short8 v0 = *(const short8*)p;
    short8 v1 = *(const short8*)(p + 512);
    float4 r0, r1;
    r0.x = fmaxf(b2f((u16)v0[0]) + b2f((u16)v1[0]), 0.f);
    r0.y = fmaxf(b2f((u16)v0[1]) + b2f((u16)v1[1]), 0.f);
    r0.z = fmaxf(b2f((u16)v0[2]) + b2f((u16)v1[2]), 0.f);
    r0.w = fmaxf(b2f((u16)v0[3]) + b2f((u16)v1[3]), 0.f);
    r1.x = fmaxf(b2f((u16)v0[4]) + b2f((u16)v1[4]), 0.f);
    r1.y = fmaxf(b2f((u16)v0[5]) + b2f((u16)v1[5]), 0.f);
    r1.z = fmaxf(b2f((u16)v0[6]) + b2f((u16)v1[6]), 0.f);
    r1.w = fmaxf(b2f((u16)v0[7]) + b2f((u16)v1[7]), 0.f);
    *(float4*)(out + f) = r0;
    *(float4*)(out + f + 4) = r1;
  }
}

extern "C" void kernel_launch(void* const* d_in, const int* in_sizes, int n_in,
                              void* d_out, int out_size, void* d_ws, size_t ws_size,
                              hipStream_t stream) {
  const float* x  = (const float*)d_in[0];
  const int* m1   = (const int*)d_in[1];
  const int* m2   = (const int*)d_in[2];
  const int* m3   = (const int*)d_in[3];
  const float* rw1 = (const float*)d_in[4];
  const float* rw2 = (const float*)d_in[5];
  const float* rw3 = (const float*)d_in[6];
  const float* W1 = (const float*)d_in[7];
  const float* b1 = (const float*)d_in[8];
  const float* W2 = (const float*)d_in[9];
  const float* b2 = (const float*)d_in[10];
  const float* W3 = (const float*)d_in[11];
  const float* b3 = (const float*)d_in[12];
  float* out = (float*)d_out;

  char* ws = (char*)d_ws;
  size_t off = 0;
  int* cnt = (int*)(ws + off); off += 24 * CNT_STRIDE * 4;
  int* bars = (int*)(ws + off); off += 16 * 4;
  u16* Wb1 = (u16*)(ws + off); off += (size_t)8 * 256 * 512 * 2;
  u16* Wb2 = (u16*)(ws + off); off += (size_t)8 * 256 * 256 * 2;
  u16* Wb3 = (u16*)(ws + off); off += (size_t)8 * 512 * 256 * 2;
  u16* tmp1 = (u16*)(ws + off); off += (size_t)T_TOKENS * 2 * 256 * 2;
  u16* tmp2 = (u16*)(ws + off); off += (size_t)T_TOKENS * 2 * 256 * 2;
  u16* tmp3 = (u16*)(ws + off); off += (size_t)T_TOKENS * 2 * 512 * 2;
  int* idxb = (int*)(ws + off); off += (size_t)3 * 8 * CAP * 4;
  float* wgtb = (float*)(ws + off); off += (size_t)3 * 8 * CAP * 4;

  hipMemsetAsync(cnt, 0, (24 * CNT_STRIDE + 16) * 4, stream);
  prep_kernel<<<256, 256, 0, stream>>>(m1, m2, m3, rw1, rw2, rw3, W1, W2, W3,
                                       Wb1, Wb2, Wb3, cnt, idxb, wgtb);
  moe_mega<<<GRID_MEGA, 256, 0, stream>>>(x, b1, b2, b3, out, cnt, bars,
                                          Wb1, Wb2, Wb3, tmp1, tmp2, tmp3, idxb, wgtb);
}